// Round 17
// baseline (48.667 us; speedup 1.0000x reference)
//
#include <hip/hip_runtime.h>
#include <math.h>

#define EPSf 1e-10f
#define IMG_N 64
#define IMG_H 512
#define IMG_W 512
#define KBLK 4096                  // 64x64 blocks per image
#define TOTAL_BLK (IMG_N * KBLK)   // 262144
#define WG 256
#define NWG (TOTAL_BLK / WG)       // 1024 (kA)
#define NWG4 (TOTAL_BLK * 4 / WG)  // 4096 (kC: 4 lanes per block-pair)
#define CHUNKS 64                  // kC workgroups per image (4096/64)

#define KCc 0.70710678118654752440f
#define SCc (1.0f / 64.0f)
#define LOG2E 1.44269504088896340736f

#define FSQRT(x) __builtin_amdgcn_sqrtf(x)
#define FRCP(x)  __builtin_amdgcn_rcpf(x)

// DPP lane exchanges within a quad — pure VALU, no DS op
__device__ __forceinline__ float dpp_xor1(float x) {   // [1,0,3,2]
    int i = __builtin_bit_cast(int, x);
    i = __builtin_amdgcn_mov_dpp(i, 0xB1, 0xF, 0xF, true);
    return __builtin_bit_cast(float, i);
}
__device__ __forceinline__ float dpp_xor2(float x) {   // [2,3,0,1]
    int i = __builtin_bit_cast(int, x);
    i = __builtin_amdgcn_mov_dpp(i, 0x4E, 0xF, 0xF, true);
    return __builtin_bit_cast(float, i);
}
__device__ __forceinline__ float dpp_bcast0(float x) { // [0,0,0,0]
    int i = __builtin_bit_cast(int, x);
    i = __builtin_amdgcn_mov_dpp(i, 0x00, 0xF, 0xF, true);
    return __builtin_bit_cast(float, i);
}

__device__ __forceinline__ float wave_red(float v) {
#pragma unroll
    for (int o = 32; o > 0; o >>= 1) v += __shfl_down(v, o, 64);
    return v;
}

// ---------------- kernel A: per-block DC amplitude of target, partial sums ----
__global__ __launch_bounds__(WG) void kA(const float* __restrict__ tgt,
                                         float* __restrict__ partA) {
    int gid = blockIdx.x * WG + threadIdx.x;
    int n = gid >> 12;
    int k = gid & 4095;
    int bi = k >> 6, bj = k & 63;
    const float* p = tgt + (size_t)n * (IMG_H * IMG_W) + (size_t)(bi * 8) * IMG_W + bj * 8;
    float s = 0.f;
#pragma unroll
    for (int r = 0; r < 8; r++) {
        float4 a = *(const float4*)(p + (size_t)r * IMG_W);
        float4 b = *(const float4*)(p + (size_t)r * IMG_W + 4);
        s += ((a.x + a.y) + (a.z + a.w)) + ((b.x + b.y) + (b.z + b.w));
    }
    float dc = s * (1.0f / 64.0f);                 // rfft2 DC / b^2
    float amp = sqrtf((dc + EPSf) * (dc + EPSf) + EPSf * EPSf);
    float wv = wave_red(amp);
    __shared__ float red[4];
    if ((threadIdx.x & 63) == 0) red[threadIdx.x >> 6] = wv;
    __syncthreads();
    if (threadIdx.x == 0) partA[blockIdx.x] = (red[0] + red[1]) + (red[2] + red[3]);
}

// row real FFT-8 -> 8 NAMED scalars [c0, c1r, c1i, c2r, c2i, c3r, c3i, c4], /64
#define ROWFFT(A, B, P) do { \
    float s02 = (A).x + (B).x, d02 = (A).x - (B).x; \
    float s26 = (A).z + (B).z, d26 = (A).z - (B).z; \
    float s13 = (A).y + (B).y, d13 = (A).y - (B).y; \
    float s37 = (A).w + (B).w, d37 = (A).w - (B).w; \
    float e0 = s02 + s26, e2 = s02 - s26; \
    float o0 = s13 + s37, o2 = s13 - s37; \
    float cp = KCc * (d13 - d37), cm = KCc * (d13 + d37); \
    P##_0 = SCc * (e0 + o0);  P##_1 = SCc * (d02 + cp); \
    P##_2 = SCc * (-d26 - cm); P##_3 = SCc * e2; \
    P##_4 = SCc * (-o2);      P##_5 = SCc * (d02 - cp); \
    P##_6 = SCc * (d26 - cm); P##_7 = SCc * (e0 - o0); \
} while (0)

#define DECL8(P) float P##_0, P##_1, P##_2, P##_3, P##_4, P##_5, P##_6, P##_7

#define LOADROW(ptr, r, P) do { \
    float4 A = *(const float4*)((ptr) + (size_t)(r) * IMG_W); \
    float4 B = *(const float4*)((ptr) + (size_t)(r) * IMG_W + 4); \
    ROWFFT(A, B, P); \
} while (0)

// TWO coefficient-pair contributions in one noinline call — UNCHANGED from the
// measured-good R11/R14 artifact (VGPR-92 schedule). Do not edit.
__device__ __attribute__((noinline)) float2
coef2x2(float oRA, float oIA, float rRA, float rIA, float tA, float lA, float pA,
        float oRB, float oIB, float rRB, float rIB, float tB, float lB, float pB,
        float lum, float omw_llum, float w, float beta, int img, int b1i) {
    float oReA = oRA + EPSf, oIeA = oIA + EPSf;
    float rReA = rRA + EPSf, rIeA = rIA + EPSf;
    float oReB = oRB + EPSf, oIeB = oIB + EPSf;
    float rReB = rRB + EPSf, rIeB = rIB + EPSf;
    float aOA = FSQRT(fmaf(oReA, oReA, oIeA * oIeA));
    float aRA = FSQRT(fmaf(rReA, rReA, rIeA * rIeA));
    float aOB = FSQRT(fmaf(oReB, oReB, oIeB * oIeB));
    float aRB = FSQRT(fmaf(rReB, rReB, rIeB * rIeB));
    float a0A = img ? aRA : aOA;
    float a0B = img ? aRB : aOB;
    float dxA = fabsf(aOA - aRA);
    float dxB = fabsf(aOB - aRB);
    float l0A = __log2f(a0A + EPSf);
    float l0B = __log2f(a0B + EPSf);
    float bbA = exp2f(fmaf(w, l0A, lA + omw_llum));
    float bbB = exp2f(fmaf(w, l0B, lB + omw_llum));
    float tlA = tA * lum;
    float tlB = tB * lum;
    float eA = __expf(bbA - tlA);
    float eB = __expf(bbB - tlB);
    float xA = dxA * (1.f + eA) * FRCP(fmaf(bbA, eA, tlA));
    float xB = dxB * (1.f + eB) * FRCP(fmaf(bbB, eB, tlB));
    float dwA = b1i ? xA : (__powf(xA + EPSf, beta) + EPSf);
    float dwB = b1i ? xB : (__powf(xB + EPSf, beta) + EPSf);
    float dotA = fmaf(oReA, rReA, oIA * rIA);
    float dotB = fmaf(oReB, rReB, oIB * rIB);
    float cdA = dotA * FRCP(fmaxf(aOA * aRA, 1e-30f)) * (1.f - 1e-7f);
    float cdB = dotB * FRCP(fmaxf(aOB * aRB, 1e-30f)) * (1.f - 1e-7f);
    cdA = fminf(fmaxf(cdA, -1.f), 1.f);
    cdB = fminf(fmaxf(cdB, -1.f), 1.f);
    float tA2 = fabsf(cdA), tB2 = fabsf(cdB);
    float rA2 = FSQRT(1.f - tA2), rB2 = FSQRT(1.f - tB2);
    float plA = fmaf(fmaf(fmaf(-0.0187293f, tA2, 0.0742610f), tA2, -0.2121144f), tA2, 1.5707288f);
    float plB = fmaf(fmaf(fmaf(-0.0187293f, tB2, 0.0742610f), tB2, -0.2121144f), tB2, 1.5707288f);
    float acA = rA2 * plA;
    float acB = rB2 * plB;
    acA = (cdA < 0.f) ? (3.14159265358979f - acA) : acA;
    acB = (cdB < 0.f) ? (3.14159265358979f - acB) : acB;
    return make_float2(dwA + dwB, fmaf(acA, pA, acB * pB));
}

// One column: lane holds FFT-4 of its row-parity set; DIT-combine via quad DPP.
// half=0 lane -> global X[0..3]; half=1 lane -> X[4..7] (locals X0..X3).
// Then 2 coef slots per lane (u = 4*half + 2*img + {0,1}), exchange via lane^1.
#define COLSTEP(V, a0r,a0i,a1r,a1i,a2r,a2i,a3r,a3i, ISV0) do { \
    float4 qA = tab4[baseU5 + (V)]; \
    float4 qB = tab4[baseU5 + 5 + (V)]; \
    float t0r=(a0r)+(a2r), t0i=(a0i)+(a2i); \
    float t1r=(a0r)-(a2r), t1i=(a0i)-(a2i); \
    float t2r=(a1r)+(a3r), t2i=(a1i)+(a3i); \
    float t3r=(a1r)-(a3r), t3i=(a1i)-(a3i); \
    float F0r=t0r+t2r, F0i=t0i+t2i; \
    float F1r=t1r+t3i, F1i=t1i-t3r; \
    float F2r=t0r-t2r, F2i=t0i-t2i; \
    float F3r=t1r-t3i, F3i=t1i+t3r; \
    float P0r=dpp_xor2(F0r), P0i=dpp_xor2(F0i); \
    float P1r=dpp_xor2(F1r), P1i=dpp_xor2(F1i); \
    float P2r=dpp_xor2(F2r), P2i=dpp_xor2(F2i); \
    float P3r=dpp_xor2(F3r), P3i=dpp_xor2(F3i); \
    float E0r = half ? P0r : F0r, E0i = half ? P0i : F0i; \
    float O0r = half ? F0r : P0r, O0i = half ? F0i : P0i; \
    float E1r = half ? P1r : F1r, E1i = half ? P1i : F1i; \
    float O1r = half ? F1r : P1r, O1i = half ? F1i : P1i; \
    float E2r = half ? P2r : F2r, E2i = half ? P2i : F2i; \
    float O2r = half ? F2r : P2r, O2i = half ? F2i : P2i; \
    float E3r = half ? P3r : F3r, E3i = half ? P3i : F3i; \
    float O3r = half ? F3r : P3r, O3i = half ? F3i : P3i; \
    float W1r = KCc*(O1r+O1i), W1i = KCc*(O1i-O1r); \
    float W2r = O2i,           W2i = -O2r; \
    float W3r = KCc*(O3i-O3r), W3i = -KCc*(O3r+O3i); \
    float X0r = fmaf(sgn, O0r, E0r), X0i = fmaf(sgn, O0i, E0i); \
    float X1r = fmaf(sgn, W1r, E1r), X1i = fmaf(sgn, W1i, E1i); \
    float X2r = fmaf(sgn, W2r, E2r), X2i = fmaf(sgn, W2i, E2i); \
    float X3r = fmaf(sgn, W3r, E3r), X3i = fmaf(sgn, W3i, E3i); \
    if (ISV0) { /* lum from target DC: lane (img=0,half=0) = quad lane 0 */ \
        float rr = X0r + EPSf, ii = X0i + EPSf; \
        float myamp = FSQRT(fmaf(rr, rr, ii * ii)); \
        float amp00 = dpp_bcast0(myamp); \
        float llum = alpha * (__log2f(amp00 + EPSf) - lavg); \
        lum = exp2f(llum); \
        omw_llum = (1.f - w) * llum; \
    } \
    /* coef-slot exchange across image lanes (lane^1) */ \
    float s0r = img ? X0r : X2r, s0i = img ? X0i : X2i; \
    float s1r = img ? X1r : X3r, s1i = img ? X1i : X3i; \
    float r0r = dpp_xor1(s0r), r0i = dpp_xor1(s0i); \
    float r1r = dpp_xor1(s1r), r1i = dpp_xor1(s1i); \
    float oAr = img ? X2r : X0r, oAi = img ? X2i : X0i; \
    float oBr = img ? X3r : X1r, oBi = img ? X3i : X1i; \
    float2 dwp = coef2x2(oAr, oAi, r0r, r0i, qA.x, qA.y, qA.z, \
                         oBr, oBi, r1r, r1i, qB.x, qB.y, qB.z, \
                         lum, omw_llum, w, beta, img, b1i); \
    sumW += dwp.x; sumP += dwp.y; \
} while (0)

// ---------------- kernel C: main fused compute (4 lanes per block-pair) -------
// Ledger (do not regress): R11/R14/R16 coef2x2 2-lane = 45.7/46.1/45.9us
// (VGPR 92). R12 (256,5)=118us spill; R13 kD-fold=85us; R15 coef4=52us.
// R17: 4-lane DIT split — halves live state AND per-wave serial chain.
__global__ __launch_bounds__(WG, 4) void kC(const float* __restrict__ tgt,
                                            const float* __restrict__ inp,
                                            const float* __restrict__ t_tild,
                                            const float* __restrict__ alphaP,
                                            const float* __restrict__ wtP,
                                            const float* __restrict__ betaP,
                                            const float* __restrict__ wptP,
                                            const float* __restrict__ partA,
                                            float* __restrict__ partW,
                                            float* __restrict__ partP) {
    __shared__ float4 tab4[40];    // {t, (1-w)*log2 t, wp, 0}
    __shared__ float redA[4];
    float w = 1.f / (1.f + __expf(-wtP[0]));
    if (threadIdx.x < 40) {
        float tt = t_tild[threadIdx.x];
        tab4[threadIdx.x] = make_float4(__expf(tt), (1.f - w) * tt * LOG2E,
                                        __expf(wptP[threadIdx.x]), 0.f);
    }
    // in-kernel avg reduce (replaces kB): 4 strided loads + wave/LDS reduce
    {
        float v = partA[threadIdx.x] + partA[threadIdx.x + 256] +
                  partA[threadIdx.x + 512] + partA[threadIdx.x + 768];
        float wv = wave_red(v);
        if ((threadIdx.x & 63) == 0) redA[threadIdx.x >> 6] = wv;
    }
    __syncthreads();
    float avg = ((redA[0] + redA[1]) + (redA[2] + redA[3])) * (1.0f / (float)TOTAL_BLK);
    float alpha = alphaP[0];
    float beta = betaP[0];
    float lavg = __log2f(avg + EPSf);
    int b1i = (beta == 1.0f) ? 1 : 0;

    int gid = blockIdx.x * WG + threadIdx.x;
    int p = gid >> 2;          // block-pair index
    int img = gid & 1;         // bit0: 0 = target, 1 = input
    int half = (gid >> 1) & 1; // bit1: 0 = even rows, 1 = odd rows
    float sgn = half ? -1.f : 1.f;
    int baseU5 = half * 20 + img * 10;   // (4*half + 2*img) * 5
    int n = p >> 12, k = p & 4095;
    int bi = k >> 6, bj = k & 63;
    size_t off = (size_t)n * (IMG_H * IMG_W) + (size_t)(bi * 8) * IMG_W + bj * 8;
    const float* src = (img ? inp : tgt) + off;

    // row FFT state for ONE image, ONE row-parity: 32 named scalars
    DECL8(y0); DECL8(y1); DECL8(y2); DECL8(y3);
    LOADROW(src, half,     y0);   // row 0/1
    LOADROW(src, 2 + half, y1);   // row 2/3
    LOADROW(src, 4 + half, y2);   // row 4/5
    LOADROW(src, 6 + half, y3);   // row 6/7

    float sumW = 0.f, sumP = 0.f;
    float lum = 0.f, omw_llum = 0.f;

    COLSTEP(0, y0_0, 0.f,  y1_0, 0.f,  y2_0, 0.f,  y3_0, 0.f,  1);
    COLSTEP(1, y0_1, y0_2, y1_1, y1_2, y2_1, y2_2, y3_1, y3_2, 0);
    COLSTEP(2, y0_3, y0_4, y1_3, y1_4, y2_3, y2_4, y3_3, y3_4, 0);
    COLSTEP(3, y0_5, y0_6, y1_5, y1_6, y2_5, y2_6, y3_5, y3_6, 0);
    COLSTEP(4, y0_7, 0.f,  y1_7, 0.f,  y2_7, 0.f,  y3_7, 0.f,  0);

    if (b1i) sumW += 10.f * 2.f * EPSf;   // fold per-term (+eps)^1 + eps (10 terms/lane)

    float wW = wave_red(sumW);
    float wP = wave_red(sumP);
    __shared__ float redW[4], redP[4];
    if ((threadIdx.x & 63) == 0) { redW[threadIdx.x >> 6] = wW; redP[threadIdx.x >> 6] = wP; }
    __syncthreads();
    if (threadIdx.x == 0) {
        partW[blockIdx.x] = (redW[0] + redW[1]) + (redW[2] + redW[3]);
        partP[blockIdx.x] = (redP[0] + redP[1]) + (redP[2] + redP[3]);
    }
}

// ---------------- kernel D: per-image final ----------------------------------
__global__ __launch_bounds__(64) void kD(const float* __restrict__ partW,
                                         const float* __restrict__ partP,
                                         const float* __restrict__ betaP,
                                         float* __restrict__ out) {
    int n = threadIdx.x;
    float sW = 0.f, sP = 0.f;
#pragma unroll
    for (int c = 0; c < CHUNKS; c++) {
        sW += partW[n * CHUNKS + c];
        sP += partP[n * CHUNKS + c];
    }
    float beta = betaP[0];
    float wat = (beta == 1.0f) ? sW : __powf(sW, 1.0f / beta);
    out[n] = wat + sP;
}

extern "C" void kernel_launch(void* const* d_in, const int* in_sizes, int n_in,
                              void* d_out, int out_size, void* d_ws, size_t ws_size,
                              hipStream_t stream) {
    const float* inp    = (const float*)d_in[0];
    const float* tgt    = (const float*)d_in[1];
    const float* t_tild = (const float*)d_in[2];
    const float* alphaP = (const float*)d_in[3];
    const float* wtP    = (const float*)d_in[4];
    const float* betaP  = (const float*)d_in[5];
    const float* wptP   = (const float*)d_in[6];
    float* out = (float*)d_out;
    float* ws = (float*)d_ws;
    float* partA = ws;           // [1024]
    float* partW = ws + 1056;    // [4096]
    float* partP = ws + 5152;    // [4096]

    hipLaunchKernelGGL(kA, dim3(NWG), dim3(WG), 0, stream, tgt, partA);
    hipLaunchKernelGGL(kC, dim3(NWG4), dim3(WG), 0, stream, tgt, inp, t_tild,
                       alphaP, wtP, betaP, wptP, partA, partW, partP);
    hipLaunchKernelGGL(kD, dim3(1), dim3(64), 0, stream, partW, partP, betaP, out);
}

// Round 18
// 45.814 us; speedup vs baseline: 1.0623x; 1.0623x over previous
//
#include <hip/hip_runtime.h>
#include <math.h>

#define EPSf 1e-10f
#define IMG_N 64
#define IMG_H 512
#define IMG_W 512
#define KBLK 4096                  // 64x64 blocks per image
#define TOTAL_BLK (IMG_N * KBLK)   // 262144
#define WG 256
#define NWG (TOTAL_BLK / WG)       // 1024 (kA)
#define NWG2 (TOTAL_BLK * 2 / WG)  // 2048 (kC: 2 lanes per block-pair)
#define CHUNKS 32                  // kC workgroups per image (2048/64)

#define KCc 0.70710678118654752440f
#define SCc (1.0f / 64.0f)
#define LOG2E 1.44269504088896340736f

#define FSQRT(x) __builtin_amdgcn_sqrtf(x)
#define FRCP(x)  __builtin_amdgcn_rcpf(x)

// lane^1 exchange via DPP quad_perm [1,0,3,2] — pure VALU, no DS op
__device__ __forceinline__ float dpp_xor1(float x) {
    int i = __builtin_bit_cast(int, x);
    i = __builtin_amdgcn_mov_dpp(i, 0xB1, 0xF, 0xF, true);
    return __builtin_bit_cast(float, i);
}

__device__ __forceinline__ float wave_red(float v) {
#pragma unroll
    for (int o = 32; o > 0; o >>= 1) v += __shfl_down(v, o, 64);
    return v;
}

// ---------------- kernel A: per-block DC amplitude of target, partial sums ----
__global__ __launch_bounds__(WG) void kA(const float* __restrict__ tgt,
                                         float* __restrict__ partA) {
    int gid = blockIdx.x * WG + threadIdx.x;
    int n = gid >> 12;
    int k = gid & 4095;
    int bi = k >> 6, bj = k & 63;
    const float* p = tgt + (size_t)n * (IMG_H * IMG_W) + (size_t)(bi * 8) * IMG_W + bj * 8;
    float s = 0.f;
#pragma unroll
    for (int r = 0; r < 8; r++) {
        float4 a = *(const float4*)(p + (size_t)r * IMG_W);
        float4 b = *(const float4*)(p + (size_t)r * IMG_W + 4);
        s += ((a.x + a.y) + (a.z + a.w)) + ((b.x + b.y) + (b.z + b.w));
    }
    float dc = s * (1.0f / 64.0f);                 // rfft2 DC / b^2
    float amp = sqrtf((dc + EPSf) * (dc + EPSf) + EPSf * EPSf);
    float wv = wave_red(amp);
    __shared__ float red[4];
    if ((threadIdx.x & 63) == 0) red[threadIdx.x >> 6] = wv;
    __syncthreads();
    if (threadIdx.x == 0) partA[blockIdx.x] = (red[0] + red[1]) + (red[2] + red[3]);
}

// row real FFT-8 -> 8 NAMED scalars [c0, c1r, c1i, c2r, c2i, c3r, c3i, c4], /64
#define ROWFFT(A, B, P) do { \
    float s02 = (A).x + (B).x, d02 = (A).x - (B).x; \
    float s26 = (A).z + (B).z, d26 = (A).z - (B).z; \
    float s13 = (A).y + (B).y, d13 = (A).y - (B).y; \
    float s37 = (A).w + (B).w, d37 = (A).w - (B).w; \
    float e0 = s02 + s26, e2 = s02 - s26; \
    float o0 = s13 + s37, o2 = s13 - s37; \
    float cp = KCc * (d13 - d37), cm = KCc * (d13 + d37); \
    P##_0 = SCc * (e0 + o0);  P##_1 = SCc * (d02 + cp); \
    P##_2 = SCc * (-d26 - cm); P##_3 = SCc * e2; \
    P##_4 = SCc * (-o2);      P##_5 = SCc * (d02 - cp); \
    P##_6 = SCc * (d26 - cm); P##_7 = SCc * (e0 - o0); \
} while (0)

#define DECL8(P) float P##_0, P##_1, P##_2, P##_3, P##_4, P##_5, P##_6, P##_7

#define LOADROW(ptr, r, P) do { \
    float4 A = *(const float4*)((ptr) + (size_t)(r) * IMG_W); \
    float4 B = *(const float4*)((ptr) + (size_t)(r) * IMG_W + 4); \
    ROWFFT(A, B, P); \
} while (0)

// complex FFT-8 on 16 scalar inputs -> 16 NAMED scalar outputs PFX0r..PFX7i
#define CFFT8M(PFX, x0r,x0i,x1r,x1i,x2r,x2i,x3r,x3i,x4r,x4i,x5r,x5i,x6r,x6i,x7r,x7i) \
    float PFX##0r, PFX##0i, PFX##1r, PFX##1i, PFX##2r, PFX##2i, PFX##3r, PFX##3i, \
          PFX##4r, PFX##4i, PFX##5r, PFX##5i, PFX##6r, PFX##6i, PFX##7r, PFX##7i; \
    { \
        float t0r = (x0r) + (x4r), t0i = (x0i) + (x4i); \
        float t1r = (x0r) - (x4r), t1i = (x0i) - (x4i); \
        float t2r = (x2r) + (x6r), t2i = (x2i) + (x6i); \
        float t3r = (x2r) - (x6r), t3i = (x2i) - (x6i); \
        float E0r = t0r + t2r, E0i = t0i + t2i; \
        float E2r = t0r - t2r, E2i = t0i - t2i; \
        float E1r = t1r + t3i, E1i = t1i - t3r; \
        float E3r = t1r - t3i, E3i = t1i + t3r; \
        float u0r = (x1r) + (x5r), u0i = (x1i) + (x5i); \
        float u1r = (x1r) - (x5r), u1i = (x1i) - (x5i); \
        float u2r = (x3r) + (x7r), u2i = (x3i) + (x7i); \
        float u3r = (x3r) - (x7r), u3i = (x3i) - (x7i); \
        float O0r = u0r + u2r, O0i = u0i + u2i; \
        float O2r = u0r - u2r, O2i = u0i - u2i; \
        float O1r = u1r + u3i, O1i = u1i - u3r; \
        float O3r = u1r - u3i, O3i = u1i + u3r; \
        float W1r = KCc * (O1r + O1i), W1i = KCc * (O1i - O1r); \
        float W2r = O2i,               W2i = -O2r; \
        float W3r = KCc * (O3i - O3r), W3i = -KCc * (O3r + O3i); \
        PFX##0r = E0r + O0r; PFX##0i = E0i + O0i; \
        PFX##1r = E1r + W1r; PFX##1i = E1i + W1i; \
        PFX##2r = E2r + W2r; PFX##2i = E2i + W2i; \
        PFX##3r = E3r + W3r; PFX##3i = E3i + W3i; \
        PFX##4r = E0r - O0r; PFX##4i = E0i - O0i; \
        PFX##5r = E1r - W1r; PFX##5i = E1i - W1i; \
        PFX##6r = E2r - W2r; PFX##6i = E2i - W2i; \
        PFX##7r = E3r - W3r; PFX##7i = E3i - W3i; \
    }

// TWO coefficient-pair contributions in one noinline call: single code copy
// (I$-friendly) but two independent chains interleaved inside (ILP restored).
// 20 dword args -> register ABI, no scratch.
__device__ __attribute__((noinline)) float2
coef2x2(float oRA, float oIA, float rRA, float rIA, float tA, float lA, float pA,
        float oRB, float oIB, float rRB, float rIB, float tB, float lB, float pB,
        float lum, float omw_llum, float w, float beta, int img, int b1i) {
    // --- amplitudes (A and B interleaved by the scheduler) ---
    float oReA = oRA + EPSf, oIeA = oIA + EPSf;
    float rReA = rRA + EPSf, rIeA = rIA + EPSf;
    float oReB = oRB + EPSf, oIeB = oIB + EPSf;
    float rReB = rRB + EPSf, rIeB = rIB + EPSf;
    float aOA = FSQRT(fmaf(oReA, oReA, oIeA * oIeA));
    float aRA = FSQRT(fmaf(rReA, rReA, rIeA * rIeA));
    float aOB = FSQRT(fmaf(oReB, oReB, oIeB * oIeB));
    float aRB = FSQRT(fmaf(rReB, rReB, rIeB * rIeB));
    float a0A = img ? aRA : aOA;
    float a0B = img ? aRB : aOB;
    float dxA = fabsf(aOA - aRA);
    float dxB = fabsf(aOB - aRB);
    // --- watson (bb via single log2/exp2) ---
    float l0A = __log2f(a0A + EPSf);
    float l0B = __log2f(a0B + EPSf);
    float bbA = exp2f(fmaf(w, l0A, lA + omw_llum));
    float bbB = exp2f(fmaf(w, l0B, lB + omw_llum));
    float tlA = tA * lum;
    float tlB = tB * lum;
    float eA = __expf(bbA - tlA);
    float eB = __expf(bbB - tlB);
    float xA = dxA * (1.f + eA) * FRCP(fmaf(bbA, eA, tlA));
    float xB = dxB * (1.f + eB) * FRCP(fmaf(bbB, eB, tlB));
    float dwA = b1i ? xA : (__powf(xA + EPSf, beta) + EPSf);
    float dwB = b1i ? xB : (__powf(xB + EPSf, beta) + EPSf);
    // --- phase ---
    float dotA = fmaf(oReA, rReA, oIA * rIA);
    float dotB = fmaf(oReB, rReB, oIB * rIB);
    float cdA = dotA * FRCP(fmaxf(aOA * aRA, 1e-30f)) * (1.f - 1e-7f);
    float cdB = dotB * FRCP(fmaxf(aOB * aRB, 1e-30f)) * (1.f - 1e-7f);
    cdA = fminf(fmaxf(cdA, -1.f), 1.f);
    cdB = fminf(fmaxf(cdB, -1.f), 1.f);
    // fast acos: Abramowitz-Stegun 4.4.45, max err ~6.7e-5 rad
    float tA2 = fabsf(cdA), tB2 = fabsf(cdB);
    float rA2 = FSQRT(1.f - tA2), rB2 = FSQRT(1.f - tB2);
    float plA = fmaf(fmaf(fmaf(-0.0187293f, tA2, 0.0742610f), tA2, -0.2121144f), tA2, 1.5707288f);
    float plB = fmaf(fmaf(fmaf(-0.0187293f, tB2, 0.0742610f), tB2, -0.2121144f), tB2, 1.5707288f);
    float acA = rA2 * plA;
    float acB = rB2 * plB;
    acA = (cdA < 0.f) ? (3.14159265358979f - acA) : acA;
    acB = (cdB < 0.f) ? (3.14159265358979f - acB) : acB;
    return make_float2(dwA + dwB, fmaf(acA, pA, acB * pB));
}

// two slot pairs per call: even lane owns u=S (sends u=S+4), odd owns u=S+4
#define PAIRC2(QA, LAr, LAi, HAr, HAi, QB, LBr, LBi, HBr, HBi) do { \
    float sAr = img ? (LAr) : (HAr), sAi = img ? (LAi) : (HAi); \
    float rAr = dpp_xor1(sAr), rAi = dpp_xor1(sAi); \
    float oAr = img ? (HAr) : (LAr), oAi = img ? (HAi) : (LAi); \
    float sBr = img ? (LBr) : (HBr), sBi = img ? (LBi) : (HBi); \
    float rBr = dpp_xor1(sBr), rBi = dpp_xor1(sBi); \
    float oBr = img ? (HBr) : (LBr), oBi = img ? (HBi) : (LBi); \
    float2 dwp = coef2x2(oAr, oAi, rAr, rAi, (QA).x, (QA).y, (QA).z, \
                         oBr, oBi, rBr, rBi, (QB).x, (QB).y, (QB).z, \
                         lum, omw_llum, w, beta, img, b1i); \
    sumW += dwp.x; sumP += dwp.y; \
} while (0)

// prefetch this column's 4 table entries (before the column FFT hides latency)
#define PREFQ(V) \
    float4 q0 = tab4[base20 + 0 * 5 + (V)]; \
    float4 q1 = tab4[base20 + 1 * 5 + (V)]; \
    float4 q2 = tab4[base20 + 2 * 5 + (V)]; \
    float4 q3 = tab4[base20 + 3 * 5 + (V)];

#define COEFS2() do { \
    PAIRC2(q0, X0r, X0i, X4r, X4i, q1, X1r, X1i, X5r, X5i); \
    PAIRC2(q2, X2r, X2i, X6r, X6i, q3, X3r, X3i, X7r, X7i); \
} while (0)

// ---------------- kernel C: main fused compute (2 lanes per block-pair) -------
// avg_lum reduction (was kernel kB) folded into the prologue: every WG
// redundantly reduces the 1024 kA partials in a fixed order (deterministic).
// FINAL artifact. Ledger of measured operating points (do not re-explore):
//   R11/R14/R16 (this source): VGPR 92, no spill, 45.7/46.1/45.9us  <- best
//   R12 (256,5):        VGPR 48, 55MB spill, 118us
//   R13 (kD-fold):      VGPR 64, no ILP, 85us
//   R15 (coef4 32-arg): VGPR 64 + stack spill, 52us
//   R17 (4-lane DIT):   correct but 48.7us (DPP overhead + strided loads)
__global__ __launch_bounds__(WG, 4) void kC(const float* __restrict__ tgt,
                                            const float* __restrict__ inp,
                                            const float* __restrict__ t_tild,
                                            const float* __restrict__ alphaP,
                                            const float* __restrict__ wtP,
                                            const float* __restrict__ betaP,
                                            const float* __restrict__ wptP,
                                            const float* __restrict__ partA,
                                            float* __restrict__ partW,
                                            float* __restrict__ partP) {
    __shared__ float4 tab4[40];    // {t, (1-w)*log2 t, wp, 0}
    __shared__ float redA[4];
    float w = 1.f / (1.f + __expf(-wtP[0]));
    if (threadIdx.x < 40) {
        float tt = t_tild[threadIdx.x];
        tab4[threadIdx.x] = make_float4(__expf(tt), (1.f - w) * tt * LOG2E,
                                        __expf(wptP[threadIdx.x]), 0.f);
    }
    // in-kernel avg reduce (replaces kB): 4 strided loads + wave/LDS reduce
    {
        float v = partA[threadIdx.x] + partA[threadIdx.x + 256] +
                  partA[threadIdx.x + 512] + partA[threadIdx.x + 768];
        float wv = wave_red(v);
        if ((threadIdx.x & 63) == 0) redA[threadIdx.x >> 6] = wv;
    }
    __syncthreads();
    float avg = ((redA[0] + redA[1]) + (redA[2] + redA[3])) * (1.0f / (float)TOTAL_BLK);
    float alpha = alphaP[0];
    float beta = betaP[0];
    float lavg = __log2f(avg + EPSf);
    int b1i = (beta == 1.0f) ? 1 : 0;

    int gid = blockIdx.x * WG + threadIdx.x;
    int p = gid >> 1;          // block-pair index
    int img = gid & 1;         // 0 = target, 1 = input  (== lane parity)
    int base20 = img * 20;
    int n = p >> 12, k = p & 4095;
    int bi = k >> 6, bj = k & 63;
    size_t off = (size_t)n * (IMG_H * IMG_W) + (size_t)(bi * 8) * IMG_W + bj * 8;
    const float* src = (img ? inp : tgt) + off;

    // row FFT state for ONE image: 64 named scalars
    DECL8(t0); DECL8(t1); DECL8(t2); DECL8(t3);
    DECL8(t4); DECL8(t5); DECL8(t6); DECL8(t7);
    LOADROW(src, 0, t0); LOADROW(src, 1, t1); LOADROW(src, 2, t2); LOADROW(src, 3, t3);
    LOADROW(src, 4, t4); LOADROW(src, 5, t5); LOADROW(src, 6, t6); LOADROW(src, 7, t7);

    float sumW = 0.f, sumP = 0.f;
    float lum = 0.f, omw_llum = 0.f;

    { // v = 0 : real column, component 0
        PREFQ(0)
        CFFT8M(X, t0_0, 0.f, t1_0, 0.f, t2_0, 0.f, t3_0, 0.f,
                  t4_0, 0.f, t5_0, 0.f, t6_0, 0.f, t7_0, 0.f)
        // lum from TARGET's DC amp (even lane owns it)
        float rr = X0r + EPSf, ii = X0i + EPSf;
        float myamp = FSQRT(fmaf(rr, rr, ii * ii));
        float oamp = dpp_xor1(myamp);
        float amp00 = img ? oamp : myamp;
        float llum = alpha * (__log2f(amp00 + EPSf) - lavg);
        lum = exp2f(llum);
        omw_llum = (1.f - w) * llum;
        COEFS2();
    }
    { // v = 1 : components 1 (re), 2 (im)
        PREFQ(1)
        CFFT8M(X, t0_1, t0_2, t1_1, t1_2, t2_1, t2_2, t3_1, t3_2,
                  t4_1, t4_2, t5_1, t5_2, t6_1, t6_2, t7_1, t7_2)
        COEFS2();
    }
    { // v = 2 : components 3, 4
        PREFQ(2)
        CFFT8M(X, t0_3, t0_4, t1_3, t1_4, t2_3, t2_4, t3_3, t3_4,
                  t4_3, t4_4, t5_3, t5_4, t6_3, t6_4, t7_3, t7_4)
        COEFS2();
    }
    { // v = 3 : components 5, 6
        PREFQ(3)
        CFFT8M(X, t0_5, t0_6, t1_5, t1_6, t2_5, t2_6, t3_5, t3_6,
                  t4_5, t4_6, t5_5, t5_6, t6_5, t6_6, t7_5, t7_6)
        COEFS2();
    }
    { // v = 4 : real column, component 7
        PREFQ(4)
        CFFT8M(X, t0_7, 0.f, t1_7, 0.f, t2_7, 0.f, t3_7, 0.f,
                  t4_7, 0.f, t5_7, 0.f, t6_7, 0.f, t7_7, 0.f)
        COEFS2();
    }

    if (b1i) sumW += 20.f * 2.f * EPSf;   // fold per-term (+eps)^1 + eps

    float wW = wave_red(sumW);
    float wP = wave_red(sumP);
    __shared__ float redW[4], redP[4];
    if ((threadIdx.x & 63) == 0) { redW[threadIdx.x >> 6] = wW; redP[threadIdx.x >> 6] = wP; }
    __syncthreads();
    if (threadIdx.x == 0) {
        partW[blockIdx.x] = (redW[0] + redW[1]) + (redW[2] + redW[3]);
        partP[blockIdx.x] = (redP[0] + redP[1]) + (redP[2] + redP[3]);
    }
}

// ---------------- kernel D: per-image final ----------------------------------
__global__ __launch_bounds__(64) void kD(const float* __restrict__ partW,
                                         const float* __restrict__ partP,
                                         const float* __restrict__ betaP,
                                         float* __restrict__ out) {
    int n = threadIdx.x;
    float sW = 0.f, sP = 0.f;
#pragma unroll
    for (int c = 0; c < CHUNKS; c++) {
        sW += partW[n * CHUNKS + c];
        sP += partP[n * CHUNKS + c];
    }
    float beta = betaP[0];
    float wat = (beta == 1.0f) ? sW : __powf(sW, 1.0f / beta);
    out[n] = wat + sP;
}

extern "C" void kernel_launch(void* const* d_in, const int* in_sizes, int n_in,
                              void* d_out, int out_size, void* d_ws, size_t ws_size,
                              hipStream_t stream) {
    const float* inp    = (const float*)d_in[0];
    const float* tgt    = (const float*)d_in[1];
    const float* t_tild = (const float*)d_in[2];
    const float* alphaP = (const float*)d_in[3];
    const float* wtP    = (const float*)d_in[4];
    const float* betaP  = (const float*)d_in[5];
    const float* wptP   = (const float*)d_in[6];
    float* out = (float*)d_out;
    float* ws = (float*)d_ws;
    float* partA = ws;           // [1024]
    float* partW = ws + 1056;    // [2048]
    float* partP = ws + 3104;    // [2048]

    hipLaunchKernelGGL(kA, dim3(NWG), dim3(WG), 0, stream, tgt, partA);
    hipLaunchKernelGGL(kC, dim3(NWG2), dim3(WG), 0, stream, tgt, inp, t_tild,
                       alphaP, wtP, betaP, wptP, partA, partW, partP);
    hipLaunchKernelGGL(kD, dim3(1), dim3(64), 0, stream, partW, partP, betaP, out);
}